// Round 6
// baseline (9508.050 us; speedup 1.0000x reference)
//
#include <hip/hip_runtime.h>

#define TT 512
#define II 128
#define HH 1024
#define BB 64

typedef __attribute__((ext_vector_type(8))) short bf16x8;
typedef __attribute__((ext_vector_type(4))) float f32x4;

__device__ __forceinline__ unsigned short f2bf(float f) {
  unsigned u = __builtin_bit_cast(unsigned, f);
  u += 0x7fffu + ((u >> 16) & 1u);   // round-to-nearest-even
  return (unsigned short)(u >> 16);
}

__device__ __forceinline__ bf16x8 load8f_bf(const float* p) {
  const f32x4* q = (const f32x4*)p;
  f32x4 a = q[0];
  f32x4 b = q[1];
  bf16x8 r;
  r[0] = (short)f2bf(a[0]); r[1] = (short)f2bf(a[1]);
  r[2] = (short)f2bf(a[2]); r[3] = (short)f2bf(a[3]);
  r[4] = (short)f2bf(b[0]); r[5] = (short)f2bf(b[1]);
  r[6] = (short)f2bf(b[2]); r[7] = (short)f2bf(b[3]);
  return r;
}

__device__ __forceinline__ float sigm(float v) { return 1.f / (1.f + __expf(-v)); }
__device__ __forceinline__ float tanh_f(float v) { return 2.f / (1.f + __expf(-2.f * v)) - 1.f; }

// Monotonic group barrier, fan-in 128. Agent-scope release fence before
// arrival publishes this CU's writes; acquire fence after release
// invalidates L1/L2 before consuming. (Pattern verified rounds 1-5.)
__device__ __forceinline__ void group_barrier(int* bar, int g, int target) {
  __syncthreads();
  if (threadIdx.x == 0) {
    __builtin_amdgcn_fence(__ATOMIC_RELEASE, "agent");
    int* ctr  = bar + g * 64;
    int* flag = bar + g * 64 + 32;
    int v = __hip_atomic_fetch_add(ctr, 1, __ATOMIC_RELAXED, __HIP_MEMORY_SCOPE_AGENT);
    if (v == 127) {
      __hip_atomic_store(ctr, 0, __ATOMIC_RELAXED, __HIP_MEMORY_SCOPE_AGENT);
      __hip_atomic_store(flag, target, __ATOMIC_RELEASE, __HIP_MEMORY_SCOPE_AGENT);
    } else {
      while (__hip_atomic_load(flag, __ATOMIC_RELAXED, __HIP_MEMORY_SCOPE_AGENT) < target) {
        __builtin_amdgcn_s_sleep(2);
      }
    }
    __builtin_amdgcn_fence(__ATOMIC_ACQUIRE, "agent");
  }
  __syncthreads();
}

// 256 WGs x 256 threads (4 waves), 1 WG/CU. 2 groups x 128 WGs; group g owns
// batches [32g, 32g+32). WG owns 8 hidden units per layer (32 gate-rows each).
// Wave wv = K-quarter of BOTH layers; m-loop over 2 batch-tiles inside.
//
// ROUNDS 2-5 EVIDENCE: the allocator picks a VGPR budget (128/160) below the
// weight-fragment ask regardless of launch_bounds/waves_per_eu, and
// REMATERIALIZES the weight global-load+cvt chains every phase (constant
// ~620 MB FETCH = the whole 6-9 ms). Fix: pin each resident weight fragment
// into the AGPR class with asm volatile "+a". The def becomes opaque volatile
// asm -> remat is impossible; AGPRs (256/wave, unified file) don't compete
// with the VGPR occupancy heuristic; MFMA reads B-operands from AGPRs
// directly (cdna4_isa §10). 120 AGPRs + ~100 VGPRs << 512 unified -> no spill.
__global__ __launch_bounds__(256, 1) void lstm_persistent(
    const float* __restrict__ x, const float* __restrict__ h0,
    const float* __restrict__ c0,
    const float* __restrict__ Wih0, const float* __restrict__ Whh0,
    const float* __restrict__ bih0, const float* __restrict__ bhh0,
    const float* __restrict__ Wih1, const float* __restrict__ Whh1,
    const float* __restrict__ bih1, const float* __restrict__ bhh1,
    const float* __restrict__ Wfc, const float* __restrict__ bfc,
    float* __restrict__ out, unsigned short* __restrict__ hbuf, int* __restrict__ bar)
{
  const int tid  = threadIdx.x;
  const int lane = tid & 63;
  const int wv   = tid >> 6;         // 0..3 = K-quarter
  const int bid  = blockIdx.x;
  const int g    = bid >> 7;         // group 0..1
  const int rank = bid & 127;        // 0..127
  const int gbase = g * 32;          // batch base
  const int ubase = rank * 8;        // unit base (both layers)

  unsigned short* h1s = hbuf;                  // [2][64][1024] bf16, double-buffered
  unsigned short* h2s = hbuf + 2 * BB * HH;

  __shared__ float lds_part[4][64][33];        // [kwv][row: 32 L0 + 32 L1][batch pad33]
  __shared__ float lds_bias[64];
  __shared__ float lds_out[32];
  extern __shared__ __align__(16) unsigned short lds_w[];  // 4*20*64 frags *16B = 81920B

  const int n16 = lane & 15;
  const int ko  = (lane >> 4) * 8;

  // ---- pack weights (B-frag layout: lane holds W[n=lane&15][kt*32+ko+0..7]) ----
  // Register-resident share pinned to AGPRs; stored as f32x4, bit_cast at use.
  f32x4 w0[2][9];    // L0: 2 n-tiles x 9 kt (K-quarter = 288)  -> 72 AGPRs
  f32x4 w1r[2][6];   // L1: 2 n-tiles x first 6 of 16 kt        -> 48 AGPRs
#pragma unroll
  for (int nt = 0; nt < 2; ++nt) {
    int r = nt * 16 + n16;                     // local row: unit=r>>2, gate=r&3
    int R = (r & 3) * HH + ubase + (r >> 2);   // global gate-row (i,f,g,o order)
#pragma unroll
    for (int kt = 0; kt < 9; ++kt) {
      int c = wv * 288 + kt * 32 + ko;         // col in [0,1152)
      const float* src = (c < II) ? (Wih0 + (size_t)R * II + c)
                                  : (Whh0 + (size_t)R * HH + (c - II));
      w0[nt][kt] = __builtin_bit_cast(f32x4, load8f_bf(src));
      asm volatile("" : "+a"(w0[nt][kt]));     // pin to AGPR; remat impossible
    }
#pragma unroll
    for (int kt = 0; kt < 16; ++kt) {
      int c = wv * 512 + kt * 32 + ko;         // col in [0,2048)
      const float* src = (c < HH) ? (Wih1 + (size_t)R * HH + c)
                                  : (Whh1 + (size_t)R * HH + (c - HH));
      bf16x8 f = load8f_bf(src);
      if (kt < 6) {
        w1r[nt][kt] = __builtin_bit_cast(f32x4, f);
        asm volatile("" : "+a"(w1r[nt][kt]));  // pin to AGPR
      } else {
        ((bf16x8*)lds_w)[(wv * 20 + nt * 10 + (kt - 6)) * 64 + lane] = f;
      }
    }
  }

  // combined biases -> LDS (rows 0..31 L0, 32..63 L1)
  if (tid < 64) {
    int Lr = tid >> 5, r = tid & 31;
    int R = (r & 3) * HH + ubase + (r >> 2);
    lds_bias[tid] = (Lr == 0) ? (bih0[R] + bhh0[R]) : (bih1[R] + bhh1[R]);
  }

  // epilogue mapping: 256 threads = 2 layers x 8 units x 16 batch-pairs
  const int eL  = tid >> 7;
  const int eu  = (tid >> 4) & 7;
  const int em0 = (tid & 15) * 2;
  const int u_e = ubase + eu;
  const int b0_e = gbase + em0;
  float c_a = c0[eL * BB * HH + (size_t)b0_e * HH + u_e];
  float c_b = c0[eL * BB * HH + (size_t)(b0_e + 1) * HH + u_e];
  const float wfc_r = Wfc[u_e];

  // init h double-buffers: slot 1 <- h0 (read at p=0 / p=1)
  if (rank < 32) {
    int b = gbase + rank;
    for (int u = tid; u < HH; u += 256) {
      h1s[BB * HH + b * HH + u] = f2bf(h0[0 * BB * HH + b * HH + u]);
      h2s[BB * HH + b * HH + u] = f2bf(h0[1 * BB * HH + b * HH + u]);
    }
  }
  // init out with b_fc (atomics accumulate onto it)
  if (rank == 0) {
    float bf = bfc[0];
    for (int i = tid; i < 32 * TT; i += 256)
      out[(gbase + (i >> 9)) * TT + (i & 511)] = bf;
  }

  group_barrier(bar, g, 1);

  for (int p = 0; p <= TT; ++p) {
    const bool l0act = (p < TT);
    const bool l1act = (p >= 1);
    const unsigned short* h1r = h1s + ((p - 1) & 1) * (BB * HH);  // h1[p-1]
    const unsigned short* h2r = h2s + (p & 1) * (BB * HH);        // h2[p-2]
    const int mbase = (lane >> 4) * 4;

    // ---- layer 0: A = [x[p] | h1[p-1]], K-quarter of 1152 ----
    if (l0act) {
#pragma unroll
      for (int m = 0; m < 2; ++m) {
        const int bA = gbase + m * 16 + n16;
        f32x4 a0 = (f32x4){0.f, 0.f, 0.f, 0.f};
        f32x4 a1 = (f32x4){0.f, 0.f, 0.f, 0.f};
#pragma unroll
        for (int kt = 0; kt < 9; ++kt) {
          int c = wv * 288 + kt * 32 + ko;
          bf16x8 a = (c < II)
            ? load8f_bf(x + ((size_t)bA * TT + p) * II + c)
            : *(const bf16x8*)(h1r + (size_t)bA * HH + (c - II));
          a0 = __builtin_amdgcn_mfma_f32_16x16x32_bf16(
                 a, __builtin_bit_cast(bf16x8, w0[0][kt]), a0, 0, 0, 0);
          a1 = __builtin_amdgcn_mfma_f32_16x16x32_bf16(
                 a, __builtin_bit_cast(bf16x8, w0[1][kt]), a1, 0, 0, 0);
        }
        const int mc = m * 16 + mbase;
#pragma unroll
        for (int r = 0; r < 4; ++r) {
          lds_part[wv][n16][mc + r]      = a0[r];
          lds_part[wv][16 + n16][mc + r] = a1[r];
        }
      }
    }
    // ---- layer 1: A = [h1[p-1] | h2[p-2]], K-quarter of 2048 ----
    if (l1act) {
      const unsigned short* hb = (wv < 2) ? h1r : h2r;
      const int kbase = (wv & 1) * 512;
#pragma unroll
      for (int m = 0; m < 2; ++m) {
        const int bA = gbase + m * 16 + n16;
        const unsigned short* abase = hb + (size_t)bA * HH + kbase + ko;
        f32x4 b0 = (f32x4){0.f, 0.f, 0.f, 0.f};
        f32x4 b1 = (f32x4){0.f, 0.f, 0.f, 0.f};
#pragma unroll
        for (int kt = 0; kt < 6; ++kt) {
          bf16x8 a = *(const bf16x8*)(abase + kt * 32);
          b0 = __builtin_amdgcn_mfma_f32_16x16x32_bf16(
                 a, __builtin_bit_cast(bf16x8, w1r[0][kt]), b0, 0, 0, 0);
          b1 = __builtin_amdgcn_mfma_f32_16x16x32_bf16(
                 a, __builtin_bit_cast(bf16x8, w1r[1][kt]), b1, 0, 0, 0);
        }
#pragma unroll
        for (int kt = 6; kt < 16; ++kt) {
          bf16x8 a = *(const bf16x8*)(abase + kt * 32);
          bf16x8 wa = ((const bf16x8*)lds_w)[(wv * 20 + (kt - 6)) * 64 + lane];
          bf16x8 wb = ((const bf16x8*)lds_w)[(wv * 20 + 10 + (kt - 6)) * 64 + lane];
          b0 = __builtin_amdgcn_mfma_f32_16x16x32_bf16(a, wa, b0, 0, 0, 0);
          b1 = __builtin_amdgcn_mfma_f32_16x16x32_bf16(a, wb, b1, 0, 0, 0);
        }
        const int mc = m * 16 + mbase;
#pragma unroll
        for (int r = 0; r < 4; ++r) {
          lds_part[wv][32 + n16][mc + r] = b0[r];
          lds_part[wv][48 + n16][mc + r] = b1[r];
        }
      }
    }
    if (tid < 32) lds_out[tid] = 0.f;
    __syncthreads();

    // ---- epilogue: reduce 4 K-quarters, activations, state update ----
    const bool eact = (eL == 0) ? l0act : l1act;
    if (eact) {
      const int rb = eL * 32 + eu * 4;
#pragma unroll
      for (int j = 0; j < 2; ++j) {
        const int em = em0 + j;
        float pre[4];
#pragma unroll
        for (int q = 0; q < 4; ++q) {
          float s = lds_bias[rb + q];
#pragma unroll
          for (int w2 = 0; w2 < 4; ++w2)
            s += lds_part[w2][rb + q][em];
          pre[q] = s;
        }
        float iv = sigm(pre[0]);
        float fv = sigm(pre[1]);
        float gv = tanh_f(pre[2]);
        float ov = sigm(pre[3]);
        float cc = j ? c_b : c_a;
        cc = fv * cc + iv * gv;
        float hv = ov * tanh_f(cc);
        if (j) c_b = cc; else c_a = cc;
        const int b = gbase + em;
        if (eL == 0) {
          h1s[(p & 1) * (BB * HH) + (size_t)b * HH + u_e] = f2bf(hv);        // h1[p]
        } else {
          h2s[((p - 1) & 1) * (BB * HH) + (size_t)b * HH + u_e] = f2bf(hv);  // h2[p-1]
          atomicAdd(&lds_out[em], hv * wfc_r);                               // FC partial
        }
      }
    }
    __syncthreads();
    if (l1act && tid < 32)
      atomicAdd(&out[(gbase + tid) * TT + (p - 1)], lds_out[tid]);

    if (p < TT) group_barrier(bar, g, p + 2);
  }
}

extern "C" void kernel_launch(void* const* d_in, const int* in_sizes, int n_in,
                              void* d_out, int out_size, void* d_ws, size_t ws_size,
                              hipStream_t stream) {
  (void)in_sizes; (void)n_in; (void)out_size; (void)ws_size;
  hipMemsetAsync(d_ws, 0, 4096, stream);   // barrier counters/flags
  int* bar = (int*)d_ws;
  unsigned short* hbuf = (unsigned short*)((char*)d_ws + 4096);  // 512 KB h buffers
  hipLaunchKernelGGL(lstm_persistent, dim3(256), dim3(256), 81920, stream,
      (const float*)d_in[0], (const float*)d_in[1], (const float*)d_in[2],
      (const float*)d_in[3], (const float*)d_in[4], (const float*)d_in[5],
      (const float*)d_in[6], (const float*)d_in[7], (const float*)d_in[8],
      (const float*)d_in[9], (const float*)d_in[10], (const float*)d_in[11],
      (const float*)d_in[12], (float*)d_out, hbuf, bar);
}

// Round 8
// 7670.290 us; speedup vs baseline: 1.2396x; 1.2396x over previous
//
#include <hip/hip_runtime.h>

#define TT 512
#define II 128
#define HH 1024
#define BB 64

typedef __attribute__((ext_vector_type(8))) short bf16x8;
typedef __attribute__((ext_vector_type(4))) float f32x4;

#define ROWP 1032   // LDS h-stage row pitch (1024 + 8 pad) elements
#define XROWP 136   // LDS x-stage row pitch (128 + 8 pad) elements

__device__ __forceinline__ unsigned short f2bf(float f) {
  unsigned u = __builtin_bit_cast(unsigned, f);
  u += 0x7fffu + ((u >> 16) & 1u);   // round-to-nearest-even
  return (unsigned short)(u >> 16);
}

__device__ __forceinline__ bf16x8 load8f_bf(const float* p) {
  const f32x4* q = (const f32x4*)p;
  f32x4 a = q[0];
  f32x4 b = q[1];
  bf16x8 r;
  r[0] = (short)f2bf(a[0]); r[1] = (short)f2bf(a[1]);
  r[2] = (short)f2bf(a[2]); r[3] = (short)f2bf(a[3]);
  r[4] = (short)f2bf(b[0]); r[5] = (short)f2bf(b[1]);
  r[6] = (short)f2bf(b[2]); r[7] = (short)f2bf(b[3]);
  return r;
}

__device__ __forceinline__ float sigm(float v) { return 1.f / (1.f + __expf(-v)); }
__device__ __forceinline__ float tanh_f(float v) { return 2.f / (1.f + __expf(-2.f * v)) - 1.f; }

// Monotonic group barrier, fan-in 64. Agent-scope release fence publishes
// h-writes; acquire fence invalidates L1/L2 before consuming. (Verified r1-r6.)
__device__ __forceinline__ void group_barrier(int* bar, int g, int target) {
  __syncthreads();
  if (threadIdx.x == 0) {
    __builtin_amdgcn_fence(__ATOMIC_RELEASE, "agent");
    int* ctr  = bar + g * 64;
    int* flag = bar + g * 64 + 32;
    int v = __hip_atomic_fetch_add(ctr, 1, __ATOMIC_RELAXED, __HIP_MEMORY_SCOPE_AGENT);
    if (v == 63) {
      __hip_atomic_store(ctr, 0, __ATOMIC_RELAXED, __HIP_MEMORY_SCOPE_AGENT);
      __hip_atomic_store(flag, target, __ATOMIC_RELEASE, __HIP_MEMORY_SCOPE_AGENT);
    } else {
      while (__hip_atomic_load(flag, __ATOMIC_RELAXED, __HIP_MEMORY_SCOPE_AGENT) < target) {
        __builtin_amdgcn_s_sleep(2);
      }
    }
    __builtin_amdgcn_fence(__ATOMIC_ACQUIRE, "agent");
  }
  __syncthreads();
}

// 256 WGs x 256 threads (4 waves = 1 wave/SIMD), 1 WG/CU (106 KB LDS).
// 4 groups x 64 WGs; group g owns batches [16g,16g+16). WG owns 16 hidden
// units per layer. Wave wv = K-quarter of BOTH layers (L0 K=288, L1 K=512).
//
// REGISTER REGIME (r7 post-mortem): at 1 wave/SIMD a wave may use ~512
// unified regs. Pins: w0[4][9] -> 144 arch VGPRs ("+v"), w1[4][16] -> 256
// AGPRs ("+a"). 8-wave WGs cap waves at 256 regs -> r7's 400-reg pin was
// infeasible -> NaN miscompile. 256-thread WGs with pins verified in r6.
//
// LATENCY FIX (r6 post-mortem): FETCH ~620 MB is the intrinsic post-fence
// h-broadcast, not waste; the time sink was per-wave serial cold-LLC loads.
// Phase-start cooperative staging (all 256 threads, coalesced dwordx4) turns
// that into one parallel latency epoch; compute reads LDS only.
__global__ __launch_bounds__(256, 1) void lstm_persistent(
    const float* __restrict__ x, const float* __restrict__ h0,
    const float* __restrict__ c0,
    const float* __restrict__ Wih0, const float* __restrict__ Whh0,
    const float* __restrict__ bih0, const float* __restrict__ bhh0,
    const float* __restrict__ Wih1, const float* __restrict__ Whh1,
    const float* __restrict__ bih1, const float* __restrict__ bhh1,
    const float* __restrict__ Wfc, const float* __restrict__ bfc,
    float* __restrict__ out, unsigned short* __restrict__ hbuf, int* __restrict__ bar)
{
  const int tid  = threadIdx.x;
  const int lane = tid & 63;
  const int kwv  = tid >> 6;         // wave 0..3 = K-quarter (both layers)
  const int bid  = blockIdx.x;
  const int g    = bid >> 6;         // group 0..3
  const int rank = bid & 63;
  const int gbase = g * 16;          // batch base
  const int ubase = rank * 16;       // unit base (both layers)

  unsigned short* h1s = hbuf;                  // [2][64][1024] bf16 double-buffered
  unsigned short* h2s = hbuf + 2 * BB * HH;

  __shared__ float lds_part[2][4][64][17];     // [layer][kwv][gate-row][batch pad17]
  __shared__ float lds_bias[128];
  __shared__ float lds_out[16];
  extern __shared__ __align__(16) unsigned short lds_dyn[];
  unsigned short* s_h1 = lds_dyn;              // 16 x ROWP
  unsigned short* s_h2 = lds_dyn + 16 * ROWP;  // 16 x ROWP
  unsigned short* s_x  = lds_dyn + 32 * ROWP;  // 16 x XROWP

  const int n16 = lane & 15;
  const int ko  = (lane >> 4) * 8;

  // ---- pack resident weights (B-frag: lane holds W[n=lane&15][k0+ko+0..7]) ----
  f32x4 w0p[4][9];     // L0 K-quarter: 144 arch VGPRs ("+v")
  f32x4 w1p[4][16];    // L1 K-quarter: 256 AGPRs ("+a")
#pragma unroll
  for (int nt = 0; nt < 4; ++nt) {
    int r = nt * 16 + n16;                     // local gate-row: unit=r>>2, gate=r&3
    int R = (r & 3) * HH + ubase + (r >> 2);   // global row: gate*H + unit (i,f,g,o)
#pragma unroll
    for (int kt = 0; kt < 9; ++kt) {
      int c = kwv * 288 + kt * 32 + ko;        // col in [0,1152)
      const float* src = (c < II) ? (Wih0 + (size_t)R * II + c)
                                  : (Whh0 + (size_t)R * HH + (c - II));
      w0p[nt][kt] = __builtin_bit_cast(f32x4, load8f_bf(src));
      asm volatile("" : "+v"(w0p[nt][kt]));    // pin arch VGPR; remat impossible
    }
#pragma unroll
    for (int kt = 0; kt < 16; ++kt) {
      int c = kwv * 512 + kt * 32 + ko;        // col in [0,2048)
      const float* src = (c < HH) ? (Wih1 + (size_t)R * HH + c)
                                  : (Whh1 + (size_t)R * HH + (c - HH));
      w1p[nt][kt] = __builtin_bit_cast(f32x4, load8f_bf(src));
      asm volatile("" : "+a"(w1p[nt][kt]));    // pin AGPR; remat impossible
    }
  }

  // combined biases -> LDS (rows 0..63 L0, 64..127 L1)
  if (tid < 128) {
    int Lr = tid >> 6, r = tid & 63;
    int R = (r & 3) * HH + ubase + (r >> 2);
    lds_bias[tid] = (Lr == 0) ? (bih0[R] + bhh0[R]) : (bih1[R] + bhh1[R]);
  }

  // epilogue mapping: 256 threads = 2 layers x 16 units x 8 batch-pairs
  const int eL  = tid >> 7;
  const int eu  = (tid & 127) >> 3;
  const int em0 = (tid & 7) * 2;
  const int u_e = ubase + eu;
  const int b0_e = gbase + em0;
  float c_a = c0[eL * BB * HH + (size_t)b0_e * HH + u_e];
  float c_b = c0[eL * BB * HH + (size_t)(b0_e + 1) * HH + u_e];
  const float wfc_r = Wfc[u_e];

  // init h double-buffers: slot 1 <- h0 (read at p=0 / p=1)
  if (rank < 16) {
    int b = gbase + rank;
    for (int u = tid; u < HH; u += 256) {
      h1s[BB * HH + b * HH + u] = f2bf(h0[0 * BB * HH + b * HH + u]);
      h2s[BB * HH + b * HH + u] = f2bf(h0[1 * BB * HH + b * HH + u]);
    }
  }
  // init out with b_fc (atomics accumulate onto it)
  if (rank == 0) {
    float bf = bfc[0];
    for (int i = tid; i < 16 * TT; i += 256)
      out[(gbase + (i >> 9)) * TT + (i & 511)] = bf;
  }

  group_barrier(bar, g, 1);

  for (int p = 0; p <= TT; ++p) {
    const bool l0act = (p < TT);
    const bool l1act = (p >= 1);
    const unsigned short* h1r = h1s + ((p - 1) & 1) * (BB * HH);  // h1[p-1]
    const unsigned short* h2r = h2s + (p & 1) * (BB * HH);        // h2[p-2]

    // ---- cooperative stage: h1r, h2r (64 KB) + x[p] (8 KB fp32->bf16) ----
    {
#pragma unroll
      for (int i = 0; i < 16; ++i) {
        int c   = tid + i * 256;                 // 0..4095 16B-chunks
        int sel = c >> 11;                       // 0: h1, 1: h2
        int cc  = c & 2047;
        int b   = cc >> 7;                       // batch 0..15
        int off = (cc & 127) * 8;                // element offset
        const unsigned short* src =
            (sel ? h2r : h1r) + (size_t)(gbase + b) * HH + off;
        unsigned short* dst = (sel ? s_h2 : s_h1) + b * ROWP + off;
        *(bf16x8*)dst = *(const bf16x8*)src;
      }
      int pp = l0act ? p : (TT - 1);             // clamp (unused at p=TT)
      int b  = tid >> 4;                         // batch 0..15
      int o8 = (tid & 15) * 8;                   // float col 0..120
      bf16x8 xv = load8f_bf(x + ((size_t)(gbase + b) * TT + pp) * II + o8);
      *(bf16x8*)(s_x + b * XROWP + o8) = xv;
      if (tid < 16) lds_out[tid] = 0.f;
    }
    __syncthreads();

    // ---- compute from LDS-staged A (batch row = n16) ----
    const int mbase = (lane >> 4) * 4;
    if (l0act) {
      f32x4 acc[4];
#pragma unroll
      for (int nt = 0; nt < 4; ++nt) acc[nt] = (f32x4){0.f, 0.f, 0.f, 0.f};
#pragma unroll
      for (int kt = 0; kt < 9; ++kt) {
        int c = kwv * 288 + kt * 32 + ko;
        bf16x8 a = (c < II)
          ? *(const bf16x8*)(s_x + n16 * XROWP + c)
          : *(const bf16x8*)(s_h1 + n16 * ROWP + (c - II));
#pragma unroll
        for (int nt = 0; nt < 4; ++nt)
          acc[nt] = __builtin_amdgcn_mfma_f32_16x16x32_bf16(
                      a, __builtin_bit_cast(bf16x8, w0p[nt][kt]), acc[nt], 0, 0, 0);
      }
#pragma unroll
      for (int nt = 0; nt < 4; ++nt)
#pragma unroll
        for (int r = 0; r < 4; ++r)
          lds_part[0][kwv][nt * 16 + n16][mbase + r] = acc[nt][r];
    }
    if (l1act) {
      const unsigned short* hb = (kwv < 2) ? s_h1 : s_h2;
      const int kbase = (kwv & 1) * 512;
      f32x4 acc[4];
#pragma unroll
      for (int nt = 0; nt < 4; ++nt) acc[nt] = (f32x4){0.f, 0.f, 0.f, 0.f};
#pragma unroll
      for (int kt = 0; kt < 16; ++kt) {
        bf16x8 a = *(const bf16x8*)(hb + n16 * ROWP + kbase + kt * 32 + ko);
#pragma unroll
        for (int nt = 0; nt < 4; ++nt)
          acc[nt] = __builtin_amdgcn_mfma_f32_16x16x32_bf16(
                      a, __builtin_bit_cast(bf16x8, w1p[nt][kt]), acc[nt], 0, 0, 0);
      }
#pragma unroll
      for (int nt = 0; nt < 4; ++nt)
#pragma unroll
        for (int r = 0; r < 4; ++r)
          lds_part[1][kwv][nt * 16 + n16][mbase + r] = acc[nt][r];
    }
    __syncthreads();

    // ---- epilogue: reduce 4 K-quarters, activations, state update ----
    const bool eact = (eL == 0) ? l0act : l1act;
    if (eact) {
#pragma unroll
      for (int j = 0; j < 2; ++j) {
        const int em = em0 + j;
        float pre[4];
#pragma unroll
        for (int q = 0; q < 4; ++q) {
          float s = lds_bias[eL * 64 + eu * 4 + q];
#pragma unroll
          for (int w2 = 0; w2 < 4; ++w2)
            s += lds_part[eL][w2][eu * 4 + q][em];
          pre[q] = s;
        }
        float iv = sigm(pre[0]);
        float fv = sigm(pre[1]);
        float gv = tanh_f(pre[2]);
        float ov = sigm(pre[3]);
        float cc = j ? c_b : c_a;
        cc = fv * cc + iv * gv;
        float hv = ov * tanh_f(cc);
        if (j) c_b = cc; else c_a = cc;
        const int b = gbase + em;
        if (eL == 0) {
          h1s[(p & 1) * (BB * HH) + (size_t)b * HH + u_e] = f2bf(hv);        // h1[p]
        } else {
          h2s[((p - 1) & 1) * (BB * HH) + (size_t)b * HH + u_e] = f2bf(hv);  // h2[p-1]
          atomicAdd(&lds_out[em], hv * wfc_r);                               // FC partial
        }
      }
    }
    __syncthreads();
    if (l1act && tid < 16)
      atomicAdd(&out[(gbase + tid) * TT + (p - 1)], lds_out[tid]);

    if (p < TT) group_barrier(bar, g, p + 2);
  }
}

extern "C" void kernel_launch(void* const* d_in, const int* in_sizes, int n_in,
                              void* d_out, int out_size, void* d_ws, size_t ws_size,
                              hipStream_t stream) {
  (void)in_sizes; (void)n_in; (void)out_size; (void)ws_size;
  hipMemsetAsync(d_ws, 0, 4096, stream);   // barrier counters/flags
  int* bar = (int*)d_ws;
  unsigned short* hbuf = (unsigned short*)((char*)d_ws + 4096);  // 512 KB h buffers
  const int dyn_lds = (32 * ROWP + 16 * XROWP) * 2;              // 70400 B
  hipLaunchKernelGGL(lstm_persistent, dim3(256), dim3(256), dyn_lds, stream,
      (const float*)d_in[0], (const float*)d_in[1], (const float*)d_in[2],
      (const float*)d_in[3], (const float*)d_in[4], (const float*)d_in[5],
      (const float*)d_in[6], (const float*)d_in[7], (const float*)d_in[8],
      (const float*)d_in[9], (const float*)d_in[10], (const float*)d_in[11],
      (const float*)d_in[12], (float*)d_out, hbuf, bar);
}